// Round 1
// baseline (194.197 us; speedup 1.0000x reference)
//
#include <hip/hip_runtime.h>

#define BATCH 1024
#define IN_F 4096
#define OUT_F 4096

// ---------------- LDS-tiled transpose: dst[C][R] = src[R][C] ----------------
// grid: (C/32, R/32), block: (32, 8)
__global__ __launch_bounds__(256) void transpose_k(const float* __restrict__ src,
                                                   float* __restrict__ dst,
                                                   int R, int C) {
    __shared__ float tile[32][33];  // +1 pad: conflict-free column reads
    const int tx = threadIdx.x, ty = threadIdx.y;
    const int c0 = blockIdx.x * 32, r0 = blockIdx.y * 32;
#pragma unroll
    for (int j = 0; j < 4; ++j) {
        int r = r0 + ty + j * 8;
        tile[ty + j * 8][tx] = src[(size_t)r * C + c0 + tx];  // coalesced read
    }
    __syncthreads();
#pragma unroll
    for (int j = 0; j < 4; ++j) {
        int c = c0 + ty + j * 8;
        dst[(size_t)c * R + r0 + tx] = tile[tx][ty + j * 8];  // coalesced write
    }
}

// ---------------- CSC build: histogram -> scan -> scatter ----------------
__global__ void hist_k(const int* __restrict__ cols, int nnz, int* __restrict__ cnt) {
    int k = blockIdx.x * 256 + threadIdx.x;
    if (k < nnz) atomicAdd(&cnt[cols[k]], 1);
}

// single block, 1024 threads, 4 bins/thread; Hillis-Steele over per-thread sums
__global__ __launch_bounds__(1024) void scan_k(int* __restrict__ cnt_cursor,
                                               int* __restrict__ offs) {
    __shared__ int buf[2][1024];
    const int t = threadIdx.x;
    const int c0 = t * 4;
    int v0 = cnt_cursor[c0 + 0], v1 = cnt_cursor[c0 + 1];
    int v2 = cnt_cursor[c0 + 2], v3 = cnt_cursor[c0 + 3];
    int p = v0 + v1 + v2 + v3;
    buf[0][t] = p;
    __syncthreads();
    int s = 0;
    for (int off = 1; off < 1024; off <<= 1) {
        int d = s ^ 1;
        int x = buf[s][t];
        if (t >= off) x += buf[s][t - off];
        buf[d][t] = x;
        __syncthreads();
        s = d;
    }
    int incl = buf[s][t];
    int base = incl - p;  // exclusive prefix for this thread's 4 bins
    offs[c0 + 0] = base;
    offs[c0 + 1] = base + v0;
    offs[c0 + 2] = base + v0 + v1;
    offs[c0 + 3] = base + v0 + v1 + v2;
    cnt_cursor[c0 + 0] = base;
    cnt_cursor[c0 + 1] = base + v0;
    cnt_cursor[c0 + 2] = base + v0 + v1;
    cnt_cursor[c0 + 3] = base + v0 + v1 + v2;
    if (t == 1023) offs[OUT_F] = incl;  // total == nnz
}

__global__ void scatter_k(const int* __restrict__ rows, const int* __restrict__ cols,
                          const float* __restrict__ vals, int nnz,
                          int* __restrict__ cursor,
                          int* __restrict__ csc_r, float* __restrict__ csc_v) {
    int k = blockIdx.x * 256 + threadIdx.x;
    if (k < nnz) {
        int c = cols[k];
        int pos = atomicAdd(&cursor[c], 1);
        csc_r[pos] = rows[k];
        csc_v[pos] = vals[k];
    }
}

// ---------------- main: one block per output column, no atomics ----------------
// outT[c][b] = bias[c] + sum_e v[e] * xT[r[e]][b]; 256 thr x float4 = 1024 b
__global__ __launch_bounds__(256) void spmm_k(const float* __restrict__ xT,
                                              const int* __restrict__ offs,
                                              const int* __restrict__ csc_r,
                                              const float* __restrict__ csc_v,
                                              const float* __restrict__ bias,
                                              float* __restrict__ outT) {
    const int c = blockIdx.x;
    const int t = threadIdx.x;
    const int start = offs[c], end = offs[c + 1];
    const float bb = bias[c];
    float4 acc = make_float4(bb, bb, bb, bb);
    const float4* __restrict__ x4 = (const float4*)xT;
    for (int e = start; e < end; ++e) {
        int r = csc_r[e];          // uniform across block -> 1 line/wave
        float v = csc_v[e];
        float4 xv = x4[(size_t)r * (BATCH / 4) + t];  // coalesced 4 KB/block
        acc.x = fmaf(v, xv.x, acc.x);
        acc.y = fmaf(v, xv.y, acc.y);
        acc.z = fmaf(v, xv.z, acc.z);
        acc.w = fmaf(v, xv.w, acc.w);
    }
    ((float4*)outT)[(size_t)c * (BATCH / 4) + t] = acc;  // coalesced
}

// ---------------- fallback (only if ws_size too small): atomic scatter ----------------
__global__ void bias_init_k(const float* __restrict__ bias, float* __restrict__ out) {
    int i = blockIdx.x * 256 + threadIdx.x;
    out[i] = bias[i & (OUT_F - 1)];
}
__global__ void fallback_k(const float* __restrict__ x, const float* __restrict__ vals,
                           const int* __restrict__ rows, const int* __restrict__ cols,
                           float* __restrict__ out) {
    int k = blockIdx.x;
    int r = rows[k], c = cols[k];
    float v = vals[k];
    for (int b = threadIdx.x; b < BATCH; b += 256)
        atomicAdd(&out[(size_t)b * OUT_F + c], v * x[(size_t)b * IN_F + r]);
}

extern "C" void kernel_launch(void* const* d_in, const int* in_sizes, int n_in,
                              void* d_out, int out_size, void* d_ws, size_t ws_size,
                              hipStream_t stream) {
    const float* x    = (const float*)d_in[0];
    const float* vals = (const float*)d_in[1];
    const float* bias = (const float*)d_in[2];
    const int*   rows = (const int*)d_in[3];
    const int*   cols = (const int*)d_in[4];
    float* out = (float*)d_out;
    const int nnz = in_sizes[1];

    // carve workspace
    size_t off = 0;
    auto alloc = [&](size_t bytes) {
        void* p = (char*)d_ws + off;
        off += (bytes + 255) & ~(size_t)255;
        return p;
    };
    float* xT     = (float*)alloc((size_t)IN_F * BATCH * 4);
    float* outT   = (float*)alloc((size_t)OUT_F * BATCH * 4);
    int*   offs   = (int*)alloc((OUT_F + 1) * 4);
    int*   cursor = (int*)alloc(OUT_F * 4);
    int*   csc_r  = (int*)alloc((size_t)nnz * 4);
    float* csc_v  = (float*)alloc((size_t)nnz * 4);

    if (off > ws_size) {
        // slow-but-correct path if scratch is insufficient
        bias_init_k<<<(BATCH * OUT_F) / 256, 256, 0, stream>>>(bias, out);
        fallback_k<<<nnz, 256, 0, stream>>>(x, vals, rows, cols, out);
        return;
    }

    hipMemsetAsync(cursor, 0, OUT_F * 4, stream);  // histogram counts start at 0
    transpose_k<<<dim3(IN_F / 32, BATCH / 32), dim3(32, 8), 0, stream>>>(x, xT, BATCH, IN_F);
    hist_k<<<(nnz + 255) / 256, 256, 0, stream>>>(cols, nnz, cursor);
    scan_k<<<1, 1024, 0, stream>>>(cursor, offs);
    scatter_k<<<(nnz + 255) / 256, 256, 0, stream>>>(rows, cols, vals, nnz, cursor, csc_r, csc_v);
    spmm_k<<<OUT_F, 256, 0, stream>>>(xT, offs, csc_r, csc_v, bias, outT);
    transpose_k<<<dim3(BATCH / 32, OUT_F / 32), dim3(32, 8), 0, stream>>>(outT, out, OUT_F, BATCH);
}